// Round 11
// baseline (408.579 us; speedup 1.0000x reference)
//
#include <hip/hip_runtime.h>

// Normalized correlation layer, MI355X.  B=8 H=W=32 C=64 K=5 PAD=2.
// out[b,r,w, c*160 + e*32 + f] = sum_p P1n[b,r,w,c,p] * P2n[b,r+e,f,c,p]
// Identity: sum (a-m1)(b-m2) = sum a*b - 25*m1*m2, scaled by (1/s1)(1/s2).
// R6 vs R5: store path rebuilt (H-store). R2/R4/R5 all ~140-165us kernel with
// wildly different compute => store-pattern-bound (~2.5 TB/s effective) not
// VALU/LDS. Fill (contiguous x4 streams) hits 6.2 TB/s; R3 spill traffic
// (contiguous x4 scratch) hit 5.4. So: per-wg LDS transpose (20KB staging
// unioned over dead x2s/m2s/i2s; LDS stays 28.4KB) then 5KB-contiguous
// dwordx4 streams per w (1KB contiguous per wave-store, ascending).

namespace {

constexpr int OUTC = 64 * 5 * 32; // 10240

struct PoolA {
    float x2s[8][9][36];     // rows r..r+8, 2592 floats
    float m2s[8][5][32];     // 1280
    float i2s[8][5][32];     // 1280
};
union SharedPool {
    PoolA a;
    float stage[4 * 8 * 5 * 32];  // [wi][ch][e][f] = 5120 floats (20 KB)
};

// Row-remap bases B0..B4 compile-time so win9 indexing stays in registers.
template<int B0, int B1, int B2, int B3, int B4>
__device__ __forceinline__ void compute_wg(
    const float (&win9)[9][5], const float* x1row, int wbase,
    float (&acc)[4][5])
{
    #pragma unroll
    for (int wi = 0; wi < 4; ++wi)
        #pragma unroll
        for (int e = 0; e < 5; ++e) acc[wi][e] = 0.f;

    #pragma unroll
    for (int i = 0; i < 5; ++i) {
        const float4 a0 = *reinterpret_cast<const float4*>(&x1row[i * 36 + wbase]);
        const float4 a1 = *reinterpret_cast<const float4*>(&x1row[i * 36 + wbase + 4]);
        const float A[8] = {a0.x, a0.y, a0.z, a0.w, a1.x, a1.y, a1.z, a1.w};
        #pragma unroll
        for (int j = 0; j < 5; ++j) {
            #pragma unroll
            for (int wi = 0; wi < 4; ++wi) {
                const float a = A[wi + j];
                acc[wi][0] += a * win9[B0 + i][j];
                acc[wi][1] += a * win9[B1 + i][j];
                acc[wi][2] += a * win9[B2 + i][j];
                acc[wi][3] += a * win9[B3 + i][j];
                acc[wi][4] += a * win9[B4 + i][j];
            }
        }
    }
}

__global__ __launch_bounds__(256)
void ncc_kernel(const float* __restrict__ in1, const float* __restrict__ in2,
                float* __restrict__ out) {
    // block = (b, r, c8): 8 channels; grid = 8*32*8 = 2048
    const int bid = blockIdx.x;
    const int c8 = bid & 7;
    const int r  = (bid >> 3) & 31;
    const int b  = bid >> 8;
    const int c0 = c8 * 8;

    __shared__ __align__(16) float x1s[8][5][36];          //  5.8 KB
    __shared__ __align__(16) SharedPool pool;              // 20.6 KB
    __shared__ float m1s[8][32], i1s[8][32];               //  2.0 KB

    const int tid = threadIdx.x;

    // ---- stage x1pad rows r..r+4 (float4 = 4 channels per load) ----
    for (int t = tid; t < 360; t += 256) {
        const int cg = t / 180;
        const int rem = t - cg * 180;
        const int i = rem / 36;
        const int pc = rem - i * 36;
        const int ir = r + i - 2;
        const int ic = pc - 2;
        float4 v = make_float4(0.f, 0.f, 0.f, 0.f);
        if (ir >= 0 && ir < 32 && ic >= 0 && ic < 32)
            v = *reinterpret_cast<const float4*>(&in1[((b * 32 + ir) * 32 + ic) * 64 + c0 + cg * 4]);
        x1s[cg * 4 + 0][i][pc] = v.x;
        x1s[cg * 4 + 1][i][pc] = v.y;
        x1s[cg * 4 + 2][i][pc] = v.z;
        x1s[cg * 4 + 3][i][pc] = v.w;
    }
    // ---- stage x2pad rows r..r+8 ----
    for (int t = tid; t < 648; t += 256) {
        const int cg = t / 324;
        const int rem = t - cg * 324;
        const int k = rem / 36;
        const int pc = rem - k * 36;
        const int ir = r + k - 4;
        const int ic = pc - 2;
        float4 v = make_float4(0.f, 0.f, 0.f, 0.f);
        if (ir >= 0 && ir < 32 && ic >= 0 && ic < 32)
            v = *reinterpret_cast<const float4*>(&in2[((b * 32 + ir) * 32 + ic) * 64 + c0 + cg * 4]);
        pool.a.x2s[cg * 4 + 0][k][pc] = v.x;
        pool.a.x2s[cg * 4 + 1][k][pc] = v.y;
        pool.a.x2s[cg * 4 + 2][k][pc] = v.z;
        pool.a.x2s[cg * 4 + 3][k][pc] = v.w;
    }
    __syncthreads();

    // ---- P1 patch stats: 8ch x 32w = 256 entries, one per thread ----
    {
        const int ch = tid >> 5, w = tid & 31;
        float s = 0.f, ss = 0.f;
        #pragma unroll
        for (int i = 0; i < 5; ++i)
            #pragma unroll
            for (int j = 0; j < 5; ++j) {
                const float v = x1s[ch][i][w + j];
                s += v; ss += v * v;
            }
        const float m = s * (1.0f / 25.0f);
        const float var = ss * (1.0f / 25.0f) - m * m;
        m1s[ch][w] = m;
        i1s[ch][w] = 1.0f / sqrtf(fmaxf(var, 1e-30f));
    }
    // ---- P2 patch stats: 8ch x 5e x 32f (5 per thread); remap lr<=33 ----
    for (int t = tid; t < 1280; t += 256) {
        const int ch = t / 160;
        const int rem = t - ch * 160;
        const int e = rem >> 5;
        const int f = rem & 31;
        const int bb = (r + e <= 33) ? e : e - 2;
        float s = 0.f, ss = 0.f;
        #pragma unroll
        for (int i = 0; i < 5; ++i)
            #pragma unroll
            for (int j = 0; j < 5; ++j) {
                const float v = pool.a.x2s[ch][bb + i][f + j];
                s += v; ss += v * v;
            }
        const float m = s * (1.0f / 25.0f);
        const float var = ss * (1.0f / 25.0f) - m * m;
        pool.a.m2s[ch][e][f] = m;
        pool.a.i2s[ch][e][f] = 1.0f / sqrtf(fmaxf(var, 1e-30f));
    }
    __syncthreads();

    // ---- hoist w-invariant state to registers ----
    const int lane = tid & 63;
    const int wave = tid >> 6;
    const int c2 = lane >> 5;
    const int f = lane & 31;
    const int ch = wave * 2 + c2;

    float win9[9][5];
    #pragma unroll
    for (int k = 0; k < 9; ++k) {
        const float* bp = &pool.a.x2s[ch][k][f];
        #pragma unroll
        for (int j = 0; j < 5; ++j) win9[k][j] = bp[j];
    }
    float m2v[5], i2v[5];
    #pragma unroll
    for (int e = 0; e < 5; ++e) { m2v[e] = pool.a.m2s[ch][e][f]; i2v[e] = pool.a.i2s[ch][e][f]; }
    __syncthreads();   // all reads of pool.a done before stage overwrites

    const float* x1row = &x1s[ch][0][0];
    const int rcase = (r < 30) ? 0 : (r == 30 ? 1 : 2);
    // base of this block's 5KB span for w: out[(b,r,w) row] + c0*160
    float* outbase = out + (size_t)((b * 32 + r) * 32) * OUTC + c0 * 160;

    #pragma unroll 1
    for (int wg = 0; wg < 8; ++wg) {
        const int wbase = wg * 4;
        float acc[4][5];
        if (rcase == 0)      compute_wg<0, 1, 2, 3, 4>(win9, x1row, wbase, acc);
        else if (rcase == 1) compute_wg<0, 1, 2, 3, 2>(win9, x1row, wbase, acc);
        else                 compute_wg<0, 1, 2, 1, 2>(win9, x1row, wbase, acc);

        // normalize and write to staging [wi][ch][e][f]
        #pragma unroll
        for (int wi = 0; wi < 4; ++wi) {
            const float m1 = m1s[ch][wbase + wi];
            const float i1 = i1s[ch][wbase + wi];
            #pragma unroll
            for (int e = 0; e < 5; ++e)
                pool.stage[((wi * 8 + ch) * 5 + e) * 32 + f] =
                    (acc[wi][e] - 25.0f * m1 * m2v[e]) * (i1 * i2v[e]);
        }
        __syncthreads();

        // stream out: 1280 float4 chunks, 5 per thread, ascending addresses.
        // chunk c: f4=c&7, e=(c>>3)%5, ch2=(c/40)&7, wi=c/320
        #pragma unroll
        for (int k = 0; k < 5; ++k) {
            const int c = k * 256 + tid;
            const float4 v = *reinterpret_cast<const float4*>(&pool.stage[c * 4]);
            const int f4  = c & 7;
            const int e   = (c >> 3) % 5;
            const int ch2 = (c / 40) & 7;
            const int wi  = c / 320;
            float4* dst = reinterpret_cast<float4*>(
                outbase + (size_t)(wbase + wi) * OUTC + ch2 * 160 + e * 32 + f4 * 4);
            *dst = v;
        }
        __syncthreads();   // staging reusable for next wg
    }
}

} // namespace

extern "C" void kernel_launch(void* const* d_in, const int* in_sizes, int n_in,
                              void* d_out, int out_size, void* d_ws, size_t ws_size,
                              hipStream_t stream) {
    const float* in1 = (const float*)d_in[0];
    const float* in2 = (const float*)d_in[1];
    float* out = (float*)d_out;
    // grid = B(8) * r(32) * c8(8) = 2048 blocks
    hipLaunchKernelGGL(ncc_kernel, dim3(2048), dim3(256), 0, stream, in1, in2, out);
}